// Round 1
// baseline (530.280 us; speedup 1.0000x reference)
//
#include <hip/hip_runtime.h>
#include <stdint.h>

// ---------------- DPP 64-lane reduction helpers ----------------
template<int CTRL>
__device__ __forceinline__ float dppMove(float v, float ident) {
  return __int_as_float(__builtin_amdgcn_update_dpp(
      __float_as_int(ident), __float_as_int(v), CTRL, 0xf, 0xf, false));
}
// after this, lanes 48..63 (in particular 63) hold the full 64-lane sum
__device__ __forceinline__ float waveSum63(float v) {
  v += dppMove<0x128>(v, 0.f);   // row_ror:8
  v += dppMove<0x124>(v, 0.f);   // row_ror:4
  v += dppMove<0x122>(v, 0.f);   // row_ror:2
  v += dppMove<0x121>(v, 0.f);   // row_ror:1  -> each row(16) has row sum
  v += dppMove<0x142>(v, 0.f);   // row_bcast15
  v += dppMove<0x143>(v, 0.f);   // row_bcast31
  return v;
}
__device__ __forceinline__ float waveMax63(float v) {
  v = fmaxf(v, dppMove<0x128>(v, -3e38f));
  v = fmaxf(v, dppMove<0x124>(v, -3e38f));
  v = fmaxf(v, dppMove<0x122>(v, -3e38f));
  v = fmaxf(v, dppMove<0x121>(v, -3e38f));
  v = fmaxf(v, dppMove<0x142>(v, -3e38f));
  v = fmaxf(v, dppMove<0x143>(v, -3e38f));
  return v;
}
__device__ __forceinline__ float bcast63(float v) {
  return __int_as_float(__builtin_amdgcn_readlane(__float_as_int(v), 63));
}
__device__ __forceinline__ ushort f2bf(float f) {
  uint32_t b = __float_as_uint(f);
  uint32_t r = (b + 0x7fffu + ((b >> 16) & 1u)) >> 16;
  return (ushort)r;
}

// ---------------- kA: Mt[n][d] = sum_e Wq[h][e][d] * Wk[h][e][dk], n=h*256+dk
__global__ __launch_bounds__(256)
void mhna_kA(const float* __restrict__ Wq, const float* __restrict__ Wk,
             float* __restrict__ Mt) {
  const int n = blockIdx.x;            // 0..511
  const int h = n >> 8, dk = n & 255;
  const int t = threadIdx.x;           // d (center dim)
  float acc = 0.f;
  for (int e = 0; e < 128; ++e) {
    float wkv = Wk[(size_t)(h * 128 + e) * 256 + dk];
    float wqv = Wq[(size_t)(h * 128 + e) * 256 + t];
    acc = fmaf(wqv, wkv, acc);
  }
  Mt[(size_t)n * 256 + t] = acc;
}

// ---------------- generic VALU GEMM: C[M][N] = A[M][K] * W[N][K]^T
// tiles: 128x128 per block, 8x8 per thread, K-chunks of 16
__global__ __launch_bounds__(256, 2)
void mhna_gemmNT(const float* __restrict__ A, int lda,
                 const float* __restrict__ W, int ldw,
                 float* __restrict__ C, int ldc,
                 int Ktot, int nTilesN) {
  __shared__ float As[128][17];
  __shared__ float Ws[128][17];
  const int t = threadIdx.x;
  const int nt = blockIdx.x % nTilesN;
  const int mt = blockIdx.x / nTilesN;
  const int b0 = mt * 128, n0 = nt * 128;
  const int r2 = t >> 1, cg = (t & 1) << 3;
  const int tb = t >> 4, tn = t & 15;
  float acc[8][8];
#pragma unroll
  for (int i = 0; i < 8; ++i)
#pragma unroll
    for (int u = 0; u < 8; ++u) acc[i][u] = 0.f;

  for (int kk = 0; kk < Ktot; kk += 16) {
    float4 va0 = *(const float4*)(A + (size_t)(b0 + r2) * lda + kk + cg);
    float4 va1 = *(const float4*)(A + (size_t)(b0 + r2) * lda + kk + cg + 4);
    float4 vw0 = *(const float4*)(W + (size_t)(n0 + r2) * ldw + kk + cg);
    float4 vw1 = *(const float4*)(W + (size_t)(n0 + r2) * ldw + kk + cg + 4);
    As[r2][cg + 0] = va0.x; As[r2][cg + 1] = va0.y;
    As[r2][cg + 2] = va0.z; As[r2][cg + 3] = va0.w;
    As[r2][cg + 4] = va1.x; As[r2][cg + 5] = va1.y;
    As[r2][cg + 6] = va1.z; As[r2][cg + 7] = va1.w;
    Ws[r2][cg + 0] = vw0.x; Ws[r2][cg + 1] = vw0.y;
    Ws[r2][cg + 2] = vw0.z; Ws[r2][cg + 3] = vw0.w;
    Ws[r2][cg + 4] = vw1.x; Ws[r2][cg + 5] = vw1.y;
    Ws[r2][cg + 6] = vw1.z; Ws[r2][cg + 7] = vw1.w;
    __syncthreads();
#pragma unroll
    for (int j = 0; j < 16; ++j) {
      float a8[8], w8[8];
#pragma unroll
      for (int i = 0; i < 8; ++i) a8[i] = As[tb * 8 + i][j];
#pragma unroll
      for (int u = 0; u < 8; ++u) w8[u] = Ws[tn * 8 + u][j];
#pragma unroll
      for (int i = 0; i < 8; ++i)
#pragma unroll
        for (int u = 0; u < 8; ++u) acc[i][u] = fmaf(a8[i], w8[u], acc[i][u]);
    }
    __syncthreads();
  }
#pragma unroll
  for (int i = 0; i < 8; ++i) {
    float* cp = C + (size_t)(b0 + tb * 8 + i) * ldc + n0 + tn * 8;
    *(float4*)cp = make_float4(acc[i][0], acc[i][1], acc[i][2], acc[i][3]);
    *(float4*)(cp + 4) = make_float4(acc[i][4], acc[i][5], acc[i][6], acc[i][7]);
  }
}

// ---------------- kC: per-b fused scores/softmax/ctx ----------------
__global__ __launch_bounds__(256, 2)
void mhna_kC(const float* __restrict__ nbg, const float* __restrict__ qM,
             const float* __restrict__ wts, const int* __restrict__ msk,
             float* __restrict__ ctx) {
  __shared__ ushort nb_s[64][264];   // bf16 tile, row stride 264 (pad)
  __shared__ float sc_s[2][64];
  __shared__ float at_s[2][64];
  const int b = blockIdx.x;
  const int t = threadIdx.x;
  const int w = t >> 6, lam = t & 63;

  const float4* qm4 = (const float4*)(qM + (size_t)b * 512);
  const float4 qa = qm4[lam];        // qM[b][h=0][4*lam .. +3]
  const float4 qb = qm4[64 + lam];   // qM[b][h=1][4*lam .. +3]

  const float4* nb4 = (const float4*)(nbg + (size_t)b * (64 * 256));
  float4 st[16];
#pragma unroll
  for (int r = 0; r < 16; ++r) st[r] = nb4[(r * 4 + w) * 64 + lam];

#pragma unroll
  for (int r = 0; r < 16; ++r) {
    const int k = r * 4 + w;
    float4 v = st[r];
    ushort4 u;
    u.x = f2bf(v.x); u.y = f2bf(v.y); u.z = f2bf(v.z); u.w = f2bf(v.w);
    *(ushort4*)&nb_s[k][lam * 4] = u;
    float p0 = v.x * qa.x + v.y * qa.y + v.z * qa.z + v.w * qa.w;
    float p1 = v.x * qb.x + v.y * qb.y + v.z * qb.z + v.w * qb.w;
    float s0 = waveSum63(p0);
    float s1 = waveSum63(p1);
    if (lam == 63) { sc_s[0][k] = s0; sc_s[1][k] = s1; }
  }
  __syncthreads();

  if (t < 128) {                      // wave 0 -> h=0, wave 1 -> h=1
    const int h = w;
    float s = sc_s[h][lam];
    float wv = wts[(size_t)b * 64 + lam];
    int mv = msk[(size_t)b * 64 + lam];
    s = mv ? fmaf(s, 0.08838834764831845f, wv) : -1e9f;
    float mx = bcast63(waveMax63(s));
    float e = __expf(s - mx);
    float sm = bcast63(waveSum63(e));
    at_s[h][lam] = e / sm;
  }
  __syncthreads();

  // ctx: lane owns feature d = t for both heads
  float a0 = at_s[0][lam], a1 = at_s[1][lam];
  float acc0 = 0.f, acc1 = 0.f;
#pragma unroll
  for (int k = 0; k < 64; ++k) {
    float v = __uint_as_float(((uint32_t)nb_s[k][t]) << 16);
    float c0 = __int_as_float(__builtin_amdgcn_readlane(__float_as_int(a0), k));
    float c1 = __int_as_float(__builtin_amdgcn_readlane(__float_as_int(a1), k));
    acc0 = fmaf(c0, v, acc0);
    acc1 = fmaf(c1, v, acc1);
  }
  float* cp = ctx + (size_t)b * 512;
  cp[t] = acc0;          // multi_ctx[b][0*256 + d]
  cp[256 + t] = acc1;    // multi_ctx[b][1*256 + d]
}

// ---------------- kD2: gate = sigmoid(center@Wg1^T + P@Wg2^T); blend ----------
__global__ __launch_bounds__(256, 2)
void mhna_kD2(const float* __restrict__ center, const float* __restrict__ P,
              const float* __restrict__ Wg, float* __restrict__ out) {
  __shared__ float As[128][17];
  __shared__ float Ws[128][17];
  const int t = threadIdx.x;
  const int nt = blockIdx.x & 1;
  const int mt = blockIdx.x >> 1;
  const int b0 = mt * 128, n0 = nt * 128;
  const int r2 = t >> 1, cg = (t & 1) << 3;
  const int tb = t >> 4, tn = t & 15;
  float acc[8][8];
#pragma unroll
  for (int i = 0; i < 8; ++i)
#pragma unroll
    for (int u = 0; u < 8; ++u) acc[i][u] = 0.f;

  for (int pass = 0; pass < 2; ++pass) {
    const float* Ap = pass ? P : center;
    const int wo = pass * 256;
    for (int kk = 0; kk < 256; kk += 16) {
      float4 va0 = *(const float4*)(Ap + (size_t)(b0 + r2) * 256 + kk + cg);
      float4 va1 = *(const float4*)(Ap + (size_t)(b0 + r2) * 256 + kk + cg + 4);
      float4 vw0 = *(const float4*)(Wg + (size_t)(n0 + r2) * 512 + wo + kk + cg);
      float4 vw1 = *(const float4*)(Wg + (size_t)(n0 + r2) * 512 + wo + kk + cg + 4);
      As[r2][cg + 0] = va0.x; As[r2][cg + 1] = va0.y;
      As[r2][cg + 2] = va0.z; As[r2][cg + 3] = va0.w;
      As[r2][cg + 4] = va1.x; As[r2][cg + 5] = va1.y;
      As[r2][cg + 6] = va1.z; As[r2][cg + 7] = va1.w;
      Ws[r2][cg + 0] = vw0.x; Ws[r2][cg + 1] = vw0.y;
      Ws[r2][cg + 2] = vw0.z; Ws[r2][cg + 3] = vw0.w;
      Ws[r2][cg + 4] = vw1.x; Ws[r2][cg + 5] = vw1.y;
      Ws[r2][cg + 6] = vw1.z; Ws[r2][cg + 7] = vw1.w;
      __syncthreads();
#pragma unroll
      for (int j = 0; j < 16; ++j) {
        float a8[8], w8[8];
#pragma unroll
        for (int i = 0; i < 8; ++i) a8[i] = As[tb * 8 + i][j];
#pragma unroll
        for (int u = 0; u < 8; ++u) w8[u] = Ws[tn * 8 + u][j];
#pragma unroll
        for (int i = 0; i < 8; ++i)
#pragma unroll
          for (int u = 0; u < 8; ++u) acc[i][u] = fmaf(a8[i], w8[u], acc[i][u]);
      }
      __syncthreads();
    }
  }
#pragma unroll
  for (int i = 0; i < 8; ++i) {
    const int bb = b0 + tb * 8 + i;
    const float* cp = center + (size_t)bb * 256 + n0 + tn * 8;
    const float* pp = P + (size_t)bb * 256 + n0 + tn * 8;
    float4 c0 = *(const float4*)cp, c1 = *(const float4*)(cp + 4);
    float4 p0 = *(const float4*)pp, p1 = *(const float4*)(pp + 4);
    float cv[8] = {c0.x, c0.y, c0.z, c0.w, c1.x, c1.y, c1.z, c1.w};
    float pv[8] = {p0.x, p0.y, p0.z, p0.w, p1.x, p1.y, p1.z, p1.w};
    float o[8];
#pragma unroll
    for (int u = 0; u < 8; ++u) {
      float g = 1.f / (1.f + __expf(-acc[i][u]));
      o[u] = g * cv[u] + (1.f - g) * pv[u];
    }
    float* op = out + (size_t)bb * 256 + n0 + tn * 8;
    *(float4*)op = make_float4(o[0], o[1], o[2], o[3]);
    *(float4*)(op + 4) = make_float4(o[4], o[5], o[6], o[7]);
  }
}

extern "C" void kernel_launch(void* const* d_in, const int* in_sizes, int n_in,
                              void* d_out, int out_size, void* d_ws, size_t ws_size,
                              hipStream_t stream) {
  const float* center = (const float*)d_in[0];
  const float* neigh  = (const float*)d_in[1];
  const float* nw     = (const float*)d_in[2];
  const int*   nm     = (const int*)d_in[3];
  const float* Wq     = (const float*)d_in[4];
  const float* Wk     = (const float*)d_in[5];
  const float* Wout   = (const float*)d_in[6];
  const float* Wgate  = (const float*)d_in[7];
  float* out = (float*)d_out;

  char* ws = (char*)d_ws;
  const size_t MT_BYTES  = (size_t)512 * 256 * 4;        // 512 KB
  const size_t QM_BYTES  = (size_t)16384 * 512 * 4;      // 32 MB
  const size_t CTX_BYTES = (size_t)16384 * 512 * 4;      // 32 MB
  float* Mt   = (float*)(ws);
  float* qM   = (float*)(ws + MT_BYTES);
  float* ctxw = (float*)(ws + MT_BYTES + QM_BYTES);
  float* Pw   = (float*)(ws + MT_BYTES + QM_BYTES + CTX_BYTES);

  mhna_kA<<<512, 256, 0, stream>>>(Wq, Wk, Mt);
  // qM = center @ Mt^T  : [16384 x 512], K=256
  mhna_gemmNT<<<512, 256, 0, stream>>>(center, 256, Mt, 256, qM, 512, 256, 4);
  // fused neighborhood attention per b
  mhna_kC<<<16384, 256, 0, stream>>>(neigh, qM, nw, nm, ctxw);
  // projected = multi_ctx @ Wout^T : [16384 x 256], K=512
  mhna_gemmNT<<<256, 256, 0, stream>>>(ctxw, 512, Wout, 512, Pw, 256, 512, 2);
  // gate + blend
  mhna_kD2<<<256, 256, 0, stream>>>(center, Pw, Wgate, out);
}

// Round 3
// 318.535 us; speedup vs baseline: 1.6647x; 1.6647x over previous
//
#include <hip/hip_runtime.h>
#include <stdint.h>

typedef __attribute__((ext_vector_type(8))) short bf8;   // 8 bf16 = 4 VGPRs
typedef __attribute__((ext_vector_type(4))) float f4;

// ---------------- DPP 64-lane reduction helpers ----------------
template<int CTRL>
__device__ __forceinline__ float dppMove(float v, float ident) {
  return __int_as_float(__builtin_amdgcn_update_dpp(
      __float_as_int(ident), __float_as_int(v), CTRL, 0xf, 0xf, false));
}
__device__ __forceinline__ float waveSum63(float v) {
  v += dppMove<0x128>(v, 0.f);   // row_ror:8
  v += dppMove<0x124>(v, 0.f);   // row_ror:4
  v += dppMove<0x122>(v, 0.f);   // row_ror:2
  v += dppMove<0x121>(v, 0.f);   // row_ror:1
  v += dppMove<0x142>(v, 0.f);   // row_bcast15
  v += dppMove<0x143>(v, 0.f);   // row_bcast31
  return v;                      // lane 63 holds full sum
}
__device__ __forceinline__ float waveMax63(float v) {
  v = fmaxf(v, dppMove<0x128>(v, -3e38f));
  v = fmaxf(v, dppMove<0x124>(v, -3e38f));
  v = fmaxf(v, dppMove<0x122>(v, -3e38f));
  v = fmaxf(v, dppMove<0x121>(v, -3e38f));
  v = fmaxf(v, dppMove<0x142>(v, -3e38f));
  v = fmaxf(v, dppMove<0x143>(v, -3e38f));
  return v;
}
__device__ __forceinline__ float bcast63(float v) {
  return __int_as_float(__builtin_amdgcn_readlane(__float_as_int(v), 63));
}
__device__ __forceinline__ ushort f2bf(float f) {
  uint32_t b = __float_as_uint(f);
  uint32_t r = (b + 0x7fffu + ((b >> 16) & 1u)) >> 16;
  return (ushort)r;
}

// ---------------- f32 -> bf16 cast (vectorized) ----------------
__global__ __launch_bounds__(256)
void mhna_cast(const float* __restrict__ s, ushort* __restrict__ d, int n4) {
  int i = blockIdx.x * blockDim.x + threadIdx.x;
  const int stride = gridDim.x * blockDim.x;
  for (; i < n4; i += stride) {
    float4 v = ((const float4*)s)[i];
    ushort4 u;
    u.x = f2bf(v.x); u.y = f2bf(v.y); u.z = f2bf(v.z); u.w = f2bf(v.w);
    ((ushort4*)d)[i] = u;
  }
}

// ---------------- kA: Mtb[n][d] = sum_e Wq[h][e][d]*Wk[h][e][dk], n=h*256+dk (bf16 out)
__global__ __launch_bounds__(256)
void mhna_kA(const float* __restrict__ Wq, const float* __restrict__ Wk,
             ushort* __restrict__ Mtb) {
  const int n = blockIdx.x;            // 0..511
  const int h = n >> 8, dk = n & 255;
  const int t = threadIdx.x;           // d
  float acc = 0.f;
  for (int e = 0; e < 128; ++e) {
    float wkv = Wk[(size_t)(h * 128 + e) * 256 + dk];
    float wqv = Wq[(size_t)(h * 128 + e) * 256 + t];
    acc = fmaf(wqv, wkv, acc);
  }
  Mtb[(size_t)n * 256 + t] = f2bf(acc);
}

// ---------------- MFMA GEMM: C[M][N] = A[M][K](bf16) @ W[N][K](bf16)^T
// block = 64 rows x NCOLS, 8 waves; wave w owns cols [w*NC, w*NC+NC), all 64 rows.
// A frag: row = lane&15, k = (lane>>4)*8 + j (8 contiguous bf16 = 16B)
// B frag: col = lane&15, k likewise (W row-major in K -> contiguous)
// D frag: col = lane&15, row = (lane>>4)*4 + r   [m89-verified]
// MODE 0: write C f32 (ldc=NCOLS)
// MODE 1: write C f32 (ldc=256) + Cb bf16
// MODE 2: two K-passes (A=center_bf woff=0, A2=P_bf woff=256); epilogue
//         gate=sigmoid(acc); out = gate*centerF + (1-gate)*Pf
template<int NCOLS, int KT, int MODE>
__global__ __launch_bounds__(512)
void mfma_nt(const ushort* __restrict__ A, const ushort* __restrict__ A2, int lda,
             const ushort* __restrict__ W, int ldw,
             float* __restrict__ C, ushort* __restrict__ Cb,
             const float* __restrict__ centerF, const float* __restrict__ Pf) {
  constexpr int NC = NCOLS / 8;   // cols per wave (64 or 32)
  constexpr int NT = NC / 16;     // col subtiles per wave (4 or 2)
  const int t = threadIdx.x;
  const int w = t >> 6, l = t & 63;
  const int row0 = blockIdx.x * 64;
  const int col0 = w * NC;
  const int lr = l & 15, lg = l >> 4;

  f4 acc[4][NT];
#pragma unroll
  for (int i = 0; i < 4; ++i)
#pragma unroll
    for (int j = 0; j < NT; ++j) acc[i][j] = (f4)0.f;

  constexpr int PASSES = (MODE == 2) ? 2 : 1;
#pragma unroll
  for (int p = 0; p < PASSES; ++p) {
    const ushort* Ap = (MODE == 2 && p == 1) ? A2 : A;
    const int woff = (MODE == 2) ? p * 256 : 0;
#pragma unroll 2
    for (int kk = 0; kk < KT; kk += 32) {
      bf8 af[4];
#pragma unroll
      for (int i = 0; i < 4; ++i)
        af[i] = *(const bf8*)(Ap + (size_t)(row0 + i * 16 + lr) * lda + kk + lg * 8);
#pragma unroll
      for (int j = 0; j < NT; ++j) {
        bf8 bw = *(const bf8*)(W + (size_t)(col0 + j * 16 + lr) * ldw + woff + kk + lg * 8);
#pragma unroll
        for (int i = 0; i < 4; ++i)
          acc[i][j] = __builtin_amdgcn_mfma_f32_16x16x32_bf16(af[i], bw, acc[i][j], 0, 0, 0);
      }
    }
  }

#pragma unroll
  for (int i = 0; i < 4; ++i)
#pragma unroll
    for (int j = 0; j < NT; ++j)
#pragma unroll
      for (int r = 0; r < 4; ++r) {
        const int row = row0 + i * 16 + lg * 4 + r;
        const int col = col0 + j * 16 + lr;
        float v = acc[i][j][r];
        if (MODE == 2) {
          float g = 1.f / (1.f + __expf(-v));
          float cv = centerF[(size_t)row * 256 + col];
          float pv = Pf[(size_t)row * 256 + col];
          C[(size_t)row * 256 + col] = g * cv + (1.f - g) * pv;
        } else if (MODE == 1) {
          C[(size_t)row * 256 + col] = v;
          Cb[(size_t)row * 256 + col] = f2bf(v);
        } else {
          C[(size_t)row * NCOLS + col] = v;
        }
      }
}

// ---------------- kC: fused scores/softmax/ctx, neighbor tile in REGISTERS
__global__ __launch_bounds__(256)
void mhna_kC(const float* __restrict__ nbg, const float* __restrict__ qM,
             const float* __restrict__ wts, const int* __restrict__ msk,
             ushort* __restrict__ ctxb) {
  __shared__ float sc_s[2][64];
  __shared__ float at_s[2][64];
  __shared__ float part[4][512];   // per-wave ctx partials [w][h*256+d]
  const int b = blockIdx.x;
  const int t = threadIdx.x;
  const int w = t >> 6, lam = t & 63;

  const float4* qm4 = (const float4*)(qM + (size_t)b * 512);
  const float4 qa = qm4[lam];        // h=0, d-slice [4lam,4lam+4)
  const float4 qb = qm4[64 + lam];   // h=1

  const float4* nb4 = (const float4*)(nbg + (size_t)b * (64 * 256));
  float4 st[16];                     // wave w holds rows k = r*4+w
#pragma unroll
  for (int r = 0; r < 16; ++r) st[r] = nb4[(r * 4 + w) * 64 + lam];

  // scores: per-lane partial dot + 64-lane DPP reduce
#pragma unroll
  for (int r = 0; r < 16; ++r) {
    const int k = r * 4 + w;
    float4 v = st[r];
    float p0 = v.x * qa.x + v.y * qa.y + v.z * qa.z + v.w * qa.w;
    float p1 = v.x * qb.x + v.y * qb.y + v.z * qb.z + v.w * qb.w;
    float s0 = waveSum63(p0);
    float s1 = waveSum63(p1);
    if (lam == 63) { sc_s[0][k] = s0; sc_s[1][k] = s1; }
  }
  __syncthreads();

  // softmax: wave 0 -> h=0, wave 1 -> h=1
  if (t < 128) {
    const int h = w;
    float s = sc_s[h][lam];
    float wv = wts[(size_t)b * 64 + lam];
    int mv = msk[(size_t)b * 64 + lam];
    s = mv ? fmaf(s, 0.08838834764831845f, wv) : -1e9f;
    float mx = bcast63(waveMax63(s));
    float e = __expf(s - mx);
    float sm = bcast63(waveSum63(e));
    at_s[h][lam] = e / sm;
  }
  __syncthreads();

  // ctx partials from registers: lane owns d-slice [4lam,4lam+4), k = r*4+w
  float c0[4] = {0.f, 0.f, 0.f, 0.f};
  float c1[4] = {0.f, 0.f, 0.f, 0.f};
#pragma unroll
  for (int r = 0; r < 16; ++r) {
    const int k = r * 4 + w;
    const float A0 = at_s[0][k];     // uniform addr -> LDS broadcast
    const float A1 = at_s[1][k];
    float4 v = st[r];
    c0[0] = fmaf(A0, v.x, c0[0]); c0[1] = fmaf(A0, v.y, c0[1]);
    c0[2] = fmaf(A0, v.z, c0[2]); c0[3] = fmaf(A0, v.w, c0[3]);
    c1[0] = fmaf(A1, v.x, c1[0]); c1[1] = fmaf(A1, v.y, c1[1]);
    c1[2] = fmaf(A1, v.z, c1[2]); c1[3] = fmaf(A1, v.w, c1[3]);
  }
  f4 p0v = {c0[0], c0[1], c0[2], c0[3]};
  f4 p1v = {c1[0], c1[1], c1[2], c1[3]};
  *(f4*)&part[w][lam * 4]       = p0v;
  *(f4*)&part[w][256 + lam * 4] = p1v;
  __syncthreads();

  // cross-wave reduce + bf16 store: thread t owns feature d = t for both heads
  float r0 = part[0][t] + part[1][t] + part[2][t] + part[3][t];
  float r1 = part[0][256 + t] + part[1][256 + t] + part[2][256 + t] + part[3][256 + t];
  ctxb[(size_t)b * 512 + t] = f2bf(r0);
  ctxb[(size_t)b * 512 + 256 + t] = f2bf(r1);
}

extern "C" void kernel_launch(void* const* d_in, const int* in_sizes, int n_in,
                              void* d_out, int out_size, void* d_ws, size_t ws_size,
                              hipStream_t stream) {
  const float* center = (const float*)d_in[0];
  const float* neigh  = (const float*)d_in[1];
  const float* nw     = (const float*)d_in[2];
  const int*   nm     = (const int*)d_in[3];
  const float* Wq     = (const float*)d_in[4];
  const float* Wk     = (const float*)d_in[5];
  const float* Wout   = (const float*)d_in[6];
  const float* Wgate  = (const float*)d_in[7];
  float* out = (float*)d_out;

  char* ws = (char*)d_ws;
  size_t off = 0;
  ushort* Mtb      = (ushort*)(ws + off); off += (size_t)512 * 256 * 2;        // 256 KB
  ushort* centerBf = (ushort*)(ws + off); off += (size_t)16384 * 256 * 2;      // 8 MB
  float*  qM       = (float*)(ws + off);  off += (size_t)16384 * 512 * 4;      // 32 MB
  ushort* ctxb     = (ushort*)(ws + off); off += (size_t)16384 * 512 * 2;      // 16 MB
  ushort* Woutb    = (ushort*)(ws + off); off += (size_t)256 * 512 * 2;        // 256 KB
  ushort* Wgb      = (ushort*)(ws + off); off += (size_t)256 * 512 * 2;        // 256 KB
  float*  Pw       = (float*)(ws + off);  off += (size_t)16384 * 256 * 4;      // 16 MB
  ushort* Pb       = (ushort*)(ws + off); off += (size_t)16384 * 256 * 2;      // 8 MB

  // casts
  mhna_cast<<<2048, 256, 0, stream>>>(center, centerBf, 16384 * 256 / 4);
  mhna_cast<<<64, 256, 0, stream>>>(Wout, Woutb, 256 * 512 / 4);
  mhna_cast<<<64, 256, 0, stream>>>(Wgate, Wgb, 256 * 512 / 4);
  // Mt = Wq^T Wk per head (bf16)
  mhna_kA<<<512, 256, 0, stream>>>(Wq, Wk, Mtb);
  // qM = center @ Mt^T : [16384 x 512] f32, K=256
  mfma_nt<512, 256, 0><<<256, 512, 0, stream>>>(centerBf, nullptr, 256, Mtb, 256,
                                                qM, nullptr, nullptr, nullptr);
  // fused neighborhood attention
  mhna_kC<<<16384, 256, 0, stream>>>(neigh, qM, nw, nm, ctxb);
  // P = multi_ctx @ Wout^T : [16384 x 256] f32 + bf16, K=512
  mfma_nt<256, 512, 1><<<256, 512, 0, stream>>>(ctxb, nullptr, 512, Woutb, 512,
                                                Pw, Pb, nullptr, nullptr);
  // gate GEMM (two K=256 passes) + fused sigmoid/blend epilogue
  mfma_nt<256, 256, 2><<<256, 512, 0, stream>>>(centerBf, Pb, 256, Wgb, 512,
                                                out, nullptr, center, Pw);
}

// Round 4
// 291.836 us; speedup vs baseline: 1.8170x; 1.0915x over previous
//
#include <hip/hip_runtime.h>
#include <stdint.h>

typedef __attribute__((ext_vector_type(8))) short bf8;   // 8 bf16 = 4 VGPRs
typedef __attribute__((ext_vector_type(4))) float f4;

// ---------------- DPP 64-lane reduction helpers ----------------
template<int CTRL>
__device__ __forceinline__ float dppMove(float v, float ident) {
  return __int_as_float(__builtin_amdgcn_update_dpp(
      __float_as_int(ident), __float_as_int(v), CTRL, 0xf, 0xf, false));
}
__device__ __forceinline__ float waveSum63(float v) {
  v += dppMove<0x128>(v, 0.f);   // row_ror:8
  v += dppMove<0x124>(v, 0.f);   // row_ror:4
  v += dppMove<0x122>(v, 0.f);   // row_ror:2
  v += dppMove<0x121>(v, 0.f);   // row_ror:1
  v += dppMove<0x142>(v, 0.f);   // row_bcast15
  v += dppMove<0x143>(v, 0.f);   // row_bcast31
  return v;                      // lane 63 holds full sum
}
__device__ __forceinline__ float waveMax63(float v) {
  v = fmaxf(v, dppMove<0x128>(v, -3e38f));
  v = fmaxf(v, dppMove<0x124>(v, -3e38f));
  v = fmaxf(v, dppMove<0x122>(v, -3e38f));
  v = fmaxf(v, dppMove<0x121>(v, -3e38f));
  v = fmaxf(v, dppMove<0x142>(v, -3e38f));
  v = fmaxf(v, dppMove<0x143>(v, -3e38f));
  return v;
}
__device__ __forceinline__ float bcast63(float v) {
  return __int_as_float(__builtin_amdgcn_readlane(__float_as_int(v), 63));
}
__device__ __forceinline__ ushort f2bf(float f) {
  uint32_t b = __float_as_uint(f);
  uint32_t r = (b + 0x7fffu + ((b >> 16) & 1u)) >> 16;
  return (ushort)r;
}
__device__ __forceinline__ float bf2f(ushort u) {
  return __uint_as_float(((uint32_t)u) << 16);
}

// ---------------- f32 -> bf16 cast (vectorized) ----------------
__global__ __launch_bounds__(256)
void mhna_cast(const float* __restrict__ s, ushort* __restrict__ d, int n4) {
  int i = blockIdx.x * blockDim.x + threadIdx.x;
  const int stride = gridDim.x * blockDim.x;
  for (; i < n4; i += stride) {
    float4 v = ((const float4*)s)[i];
    ushort4 u;
    u.x = f2bf(v.x); u.y = f2bf(v.y); u.z = f2bf(v.z); u.w = f2bf(v.w);
    ((ushort4*)d)[i] = u;
  }
}

// cast both weight matrices in one launch (each n4 float4s)
__global__ __launch_bounds__(256)
void mhna_castW(const float* __restrict__ a, const float* __restrict__ b,
                ushort* __restrict__ da, ushort* __restrict__ db, int n4) {
  int i = blockIdx.x * blockDim.x + threadIdx.x;
  const float* s = (i < n4) ? a : b;
  ushort* d = (i < n4) ? da : db;
  int j = (i < n4) ? i : i - n4;
  float4 v = ((const float4*)s)[j];
  ushort4 u;
  u.x = f2bf(v.x); u.y = f2bf(v.y); u.z = f2bf(v.z); u.w = f2bf(v.w);
  ((ushort4*)d)[j] = u;
}

// ---------------- kA: Mtb[n][d] = sum_e Wq[h][e][d]*Wk[h][e][dk], n=h*256+dk
__global__ __launch_bounds__(256)
void mhna_kA(const float* __restrict__ Wq, const float* __restrict__ Wk,
             ushort* __restrict__ Mtb) {
  const int n = blockIdx.x;            // 0..511
  const int h = n >> 8, dk = n & 255;
  const int t = threadIdx.x;           // d
  float acc = 0.f;
#pragma unroll 8
  for (int e = 0; e < 128; ++e) {
    float wkv = Wk[(size_t)(h * 128 + e) * 256 + dk];
    float wqv = Wq[(size_t)(h * 128 + e) * 256 + t];
    acc = fmaf(wqv, wkv, acc);
  }
  Mtb[(size_t)n * 256 + t] = f2bf(acc);
}

// ---------------- qM GEMM: qMb[16384][512] = centerBf @ Mtb^T (bf16 out)
// block = 64 rows x 512 cols, 8 waves; wave w owns cols [64w, 64w+64)
__global__ __launch_bounds__(512)
void gemm_qM(const ushort* __restrict__ A, const ushort* __restrict__ W,
             ushort* __restrict__ Cb) {
  const int t = threadIdx.x;
  const int w = t >> 6, l = t & 63;
  const int row0 = blockIdx.x * 64;
  const int col0 = w * 64;
  const int lr = l & 15, lg = l >> 4;

  f4 acc[4][4];
#pragma unroll
  for (int i = 0; i < 4; ++i)
#pragma unroll
    for (int j = 0; j < 4; ++j) acc[i][j] = (f4)0.f;

#pragma unroll 2
  for (int kk = 0; kk < 256; kk += 32) {
    bf8 af[4];
#pragma unroll
    for (int i = 0; i < 4; ++i)
      af[i] = *(const bf8*)(A + (size_t)(row0 + i * 16 + lr) * 256 + kk + lg * 8);
#pragma unroll
    for (int j = 0; j < 4; ++j) {
      bf8 bw = *(const bf8*)(W + (size_t)(col0 + j * 16 + lr) * 256 + kk + lg * 8);
#pragma unroll
      for (int i = 0; i < 4; ++i)
        acc[i][j] = __builtin_amdgcn_mfma_f32_16x16x32_bf16(af[i], bw, acc[i][j], 0, 0, 0);
    }
  }
#pragma unroll
  for (int i = 0; i < 4; ++i)
#pragma unroll
    for (int j = 0; j < 4; ++j)
#pragma unroll
      for (int r = 0; r < 4; ++r)
        Cb[(size_t)(row0 + i * 16 + lg * 4 + r) * 512 + col0 + j * 16 + lr] =
            f2bf(acc[i][j][r]);
}

// ---------------- kC: fused scores/softmax/ctx, neighbor tile in REGISTERS
__global__ __launch_bounds__(256)
void mhna_kC(const float* __restrict__ nbg, const ushort* __restrict__ qMb,
             const float* __restrict__ wts, const int* __restrict__ msk,
             ushort* __restrict__ ctxb) {
  __shared__ float sc_s[2][64];
  __shared__ float at_s[2][64];
  __shared__ float part[4][512];   // per-wave ctx partials [w][h*256+d]
  const int b = blockIdx.x;
  const int t = threadIdx.x;
  const int w = t >> 6, lam = t & 63;

  // qM (bf16) -> f32: lane owns d-slice [4lam, 4lam+4) per head
  const ushort4* qm4 = (const ushort4*)(qMb + (size_t)b * 512);
  ushort4 ua = qm4[lam];
  ushort4 ub = qm4[64 + lam];
  f4 qa = {bf2f(ua.x), bf2f(ua.y), bf2f(ua.z), bf2f(ua.w)};
  f4 qb = {bf2f(ub.x), bf2f(ub.y), bf2f(ub.z), bf2f(ub.w)};

  const float4* nb4 = (const float4*)(nbg + (size_t)b * (64 * 256));
  float4 st[16];                     // wave w holds rows k = r*4+w
#pragma unroll
  for (int r = 0; r < 16; ++r) st[r] = nb4[(r * 4 + w) * 64 + lam];

  // scores: per-lane partial dot + 64-lane DPP reduce
#pragma unroll
  for (int r = 0; r < 16; ++r) {
    const int k = r * 4 + w;
    float4 v = st[r];
    float p0 = v.x * qa.x + v.y * qa.y + v.z * qa.z + v.w * qa.w;
    float p1 = v.x * qb.x + v.y * qb.y + v.z * qb.z + v.w * qb.w;
    float s0 = waveSum63(p0);
    float s1 = waveSum63(p1);
    if (lam == 63) { sc_s[0][k] = s0; sc_s[1][k] = s1; }
  }
  __syncthreads();

  // softmax: wave 0 -> h=0, wave 1 -> h=1
  if (t < 128) {
    const int h = w;
    float s = sc_s[h][lam];
    float wv = wts[(size_t)b * 64 + lam];
    int mv = msk[(size_t)b * 64 + lam];
    s = mv ? fmaf(s, 0.08838834764831845f, wv) : -1e9f;
    float mx = bcast63(waveMax63(s));
    float e = __expf(s - mx);
    float sm = bcast63(waveSum63(e));
    at_s[h][lam] = e / sm;
  }
  __syncthreads();

  // ctx partials from registers: lane owns d-slice [4lam,4lam+4), k = r*4+w
  float c0[4] = {0.f, 0.f, 0.f, 0.f};
  float c1[4] = {0.f, 0.f, 0.f, 0.f};
#pragma unroll
  for (int r = 0; r < 16; ++r) {
    const int k = r * 4 + w;
    const float A0 = at_s[0][k];     // uniform addr -> LDS broadcast
    const float A1 = at_s[1][k];
    float4 v = st[r];
    c0[0] = fmaf(A0, v.x, c0[0]); c0[1] = fmaf(A0, v.y, c0[1]);
    c0[2] = fmaf(A0, v.z, c0[2]); c0[3] = fmaf(A0, v.w, c0[3]);
    c1[0] = fmaf(A1, v.x, c1[0]); c1[1] = fmaf(A1, v.y, c1[1]);
    c1[2] = fmaf(A1, v.z, c1[2]); c1[3] = fmaf(A1, v.w, c1[3]);
  }
  f4 p0v = {c0[0], c0[1], c0[2], c0[3]};
  f4 p1v = {c1[0], c1[1], c1[2], c1[3]};
  *(f4*)&part[w][lam * 4]       = p0v;
  *(f4*)&part[w][256 + lam * 4] = p1v;
  __syncthreads();

  // cross-wave reduce + bf16 store: thread t owns feature d = t for both heads
  float r0 = part[0][t] + part[1][t] + part[2][t] + part[3][t];
  float r1 = part[0][256 + t] + part[1][256 + t] + part[2][256 + t] + part[3][256 + t];
  ctxb[(size_t)b * 512 + t] = f2bf(r0);
  ctxb[(size_t)b * 512 + 256 + t] = f2bf(r1);
}

// ---------------- PG: fused P-GEMM + gate-GEMM + sigmoid blend ----------------
// block = 64 rows x 256 cols, 8 waves; wave w owns cols [32w, 32w+32)
// P tile kept in LDS f32 (never touches HBM).
#define LDP 260   // 260 % 32 == 4 -> 2-way (free) bank pattern; 16B-aligned rows
__global__ __launch_bounds__(512)
void mhna_PG(const ushort* __restrict__ ctxb, const ushort* __restrict__ Woutb,
             const ushort* __restrict__ centerBf, const ushort* __restrict__ Wgb,
             const float* __restrict__ centerF, float* __restrict__ out) {
  __shared__ float p_s[64][LDP];
  const int t = threadIdx.x;
  const int w = t >> 6, l = t & 63;
  const int row0 = blockIdx.x * 64;
  const int col0 = w * 32;
  const int lr = l & 15, lg = l >> 4;

  // ---- phase 1: P = multi_ctx @ Wout^T (K=512) ----
  f4 acc1[4][2];
#pragma unroll
  for (int i = 0; i < 4; ++i)
#pragma unroll
    for (int j = 0; j < 2; ++j) acc1[i][j] = (f4)0.f;

#pragma unroll 2
  for (int kk = 0; kk < 512; kk += 32) {
    bf8 af[4];
#pragma unroll
    for (int i = 0; i < 4; ++i)
      af[i] = *(const bf8*)(ctxb + (size_t)(row0 + i * 16 + lr) * 512 + kk + lg * 8);
#pragma unroll
    for (int j = 0; j < 2; ++j) {
      bf8 bw = *(const bf8*)(Woutb + (size_t)(col0 + j * 16 + lr) * 512 + kk + lg * 8);
#pragma unroll
      for (int i = 0; i < 4; ++i)
        acc1[i][j] = __builtin_amdgcn_mfma_f32_16x16x32_bf16(af[i], bw, acc1[i][j], 0, 0, 0);
    }
  }
#pragma unroll
  for (int i = 0; i < 4; ++i)
#pragma unroll
    for (int j = 0; j < 2; ++j)
#pragma unroll
      for (int r = 0; r < 4; ++r)
        p_s[i * 16 + lg * 4 + r][col0 + j * 16 + lr] = acc1[i][j][r];
  __syncthreads();

  // ---- phase 2: gate = center @ Wg1^T + P @ Wg2^T ----
  f4 acc2[4][2];
#pragma unroll
  for (int i = 0; i < 4; ++i)
#pragma unroll
    for (int j = 0; j < 2; ++j) acc2[i][j] = (f4)0.f;

  // pass A: center (bf16 from global), Wg cols [0,256)
#pragma unroll 2
  for (int kk = 0; kk < 256; kk += 32) {
    bf8 af[4];
#pragma unroll
    for (int i = 0; i < 4; ++i)
      af[i] = *(const bf8*)(centerBf + (size_t)(row0 + i * 16 + lr) * 256 + kk + lg * 8);
#pragma unroll
    for (int j = 0; j < 2; ++j) {
      bf8 bw = *(const bf8*)(Wgb + (size_t)(col0 + j * 16 + lr) * 512 + kk + lg * 8);
#pragma unroll
      for (int i = 0; i < 4; ++i)
        acc2[i][j] = __builtin_amdgcn_mfma_f32_16x16x32_bf16(af[i], bw, acc2[i][j], 0, 0, 0);
    }
  }
  // pass B: P (f32 from LDS -> bf16 fragments), Wg cols [256,512)
#pragma unroll 2
  for (int kk = 0; kk < 256; kk += 32) {
    bf8 af[4];
#pragma unroll
    for (int i = 0; i < 4; ++i) {
      f4 x0 = *(const f4*)&p_s[i * 16 + lr][kk + lg * 8];
      f4 x1 = *(const f4*)&p_s[i * 16 + lr][kk + lg * 8 + 4];
      bf8 a;
      a[0] = (short)f2bf(x0.x); a[1] = (short)f2bf(x0.y);
      a[2] = (short)f2bf(x0.z); a[3] = (short)f2bf(x0.w);
      a[4] = (short)f2bf(x1.x); a[5] = (short)f2bf(x1.y);
      a[6] = (short)f2bf(x1.z); a[7] = (short)f2bf(x1.w);
      af[i] = a;
    }
#pragma unroll
    for (int j = 0; j < 2; ++j) {
      bf8 bw = *(const bf8*)(Wgb + (size_t)(col0 + j * 16 + lr) * 512 + 256 + kk + lg * 8);
#pragma unroll
      for (int i = 0; i < 4; ++i)
        acc2[i][j] = __builtin_amdgcn_mfma_f32_16x16x32_bf16(af[i], bw, acc2[i][j], 0, 0, 0);
    }
  }

  // ---- epilogue: gate blend (P f32 from LDS) ----
#pragma unroll
  for (int i = 0; i < 4; ++i)
#pragma unroll
    for (int j = 0; j < 2; ++j)
#pragma unroll
      for (int r = 0; r < 4; ++r) {
        const int lrow = i * 16 + lg * 4 + r;
        const int row = row0 + lrow;
        const int col = col0 + j * 16 + lr;
        float g = 1.f / (1.f + __expf(-acc2[i][j][r]));
        float pv = p_s[lrow][col];
        float cv = centerF[(size_t)row * 256 + col];
        out[(size_t)row * 256 + col] = g * cv + (1.f - g) * pv;
      }
}

extern "C" void kernel_launch(void* const* d_in, const int* in_sizes, int n_in,
                              void* d_out, int out_size, void* d_ws, size_t ws_size,
                              hipStream_t stream) {
  const float* center = (const float*)d_in[0];
  const float* neigh  = (const float*)d_in[1];
  const float* nw     = (const float*)d_in[2];
  const int*   nm     = (const int*)d_in[3];
  const float* Wq     = (const float*)d_in[4];
  const float* Wk     = (const float*)d_in[5];
  const float* Wout   = (const float*)d_in[6];
  const float* Wgate  = (const float*)d_in[7];
  float* out = (float*)d_out;

  char* ws = (char*)d_ws;
  size_t off = 0;
  ushort* Mtb      = (ushort*)(ws + off); off += (size_t)512 * 256 * 2;        // 256 KB
  ushort* centerBf = (ushort*)(ws + off); off += (size_t)16384 * 256 * 2;      // 8 MB
  ushort* qMb      = (ushort*)(ws + off); off += (size_t)16384 * 512 * 2;      // 16 MB
  ushort* ctxb     = (ushort*)(ws + off); off += (size_t)16384 * 512 * 2;      // 16 MB
  ushort* Woutb    = (ushort*)(ws + off); off += (size_t)256 * 512 * 2;        // 256 KB
  ushort* Wgb      = (ushort*)(ws + off); off += (size_t)256 * 512 * 2;        // 256 KB

  mhna_cast<<<2048, 256, 0, stream>>>(center, centerBf, 16384 * 256 / 4);
  mhna_castW<<<256, 256, 0, stream>>>(Wout, Wgate, Woutb, Wgb, 256 * 512 / 4);
  mhna_kA<<<512, 256, 0, stream>>>(Wq, Wk, Mtb);
  // qM = center @ Mt^T : [16384 x 512] bf16, K=256
  gemm_qM<<<256, 512, 0, stream>>>(centerBf, Mtb, qMb);
  // fused neighborhood attention
  mhna_kC<<<16384, 256, 0, stream>>>(neigh, qMb, nw, nm, ctxb);
  // fused: P = ctx @ Wout^T ; gate = sigmoid([center,P] @ Wg^T) ; blend
  mhna_PG<<<256, 512, 0, stream>>>(ctxb, Woutb, centerBf, Wgb, center, out);
}

// Round 5
// 198.843 us; speedup vs baseline: 2.6668x; 1.4677x over previous
//
#include <hip/hip_runtime.h>
#include <stdint.h>

typedef __attribute__((ext_vector_type(8))) short bf8;   // 8 bf16 = 4 VGPRs
typedef __attribute__((ext_vector_type(4))) float f4;

// ---------------- DPP 64-lane reduction helpers ----------------
template<int CTRL>
__device__ __forceinline__ float dppMove(float v, float ident) {
  return __int_as_float(__builtin_amdgcn_update_dpp(
      __float_as_int(ident), __float_as_int(v), CTRL, 0xf, 0xf, false));
}
__device__ __forceinline__ float waveSum63(float v) {
  v += dppMove<0x128>(v, 0.f);   // row_ror:8
  v += dppMove<0x124>(v, 0.f);   // row_ror:4
  v += dppMove<0x122>(v, 0.f);   // row_ror:2
  v += dppMove<0x121>(v, 0.f);   // row_ror:1
  v += dppMove<0x142>(v, 0.f);   // row_bcast15
  v += dppMove<0x143>(v, 0.f);   // row_bcast31
  return v;                      // lane 63 holds full sum
}
__device__ __forceinline__ float waveMax63(float v) {
  v = fmaxf(v, dppMove<0x128>(v, -3e38f));
  v = fmaxf(v, dppMove<0x124>(v, -3e38f));
  v = fmaxf(v, dppMove<0x122>(v, -3e38f));
  v = fmaxf(v, dppMove<0x121>(v, -3e38f));
  v = fmaxf(v, dppMove<0x142>(v, -3e38f));
  v = fmaxf(v, dppMove<0x143>(v, -3e38f));
  return v;
}
__device__ __forceinline__ float bcast63(float v) {
  return __int_as_float(__builtin_amdgcn_readlane(__float_as_int(v), 63));
}
__device__ __forceinline__ ushort f2bf(float f) {
  uint32_t b = __float_as_uint(f);
  uint32_t r = (b + 0x7fffu + ((b >> 16) & 1u)) >> 16;
  return (ushort)r;
}
__device__ __forceinline__ float bf2f(ushort u) {
  return __uint_as_float(((uint32_t)u) << 16);
}

// ---------------- prologue: center cast + weight casts + kA, one launch ------
// blocks [0,2048): cast center (f32->bf16)
// blocks [2048,2304): cast Wout & Wgate
// blocks [2304,2816): Mtb[n][d] = sum_e Wq[h][e][d]*Wk[h][e][dk], n=h*256+dk
__global__ __launch_bounds__(256)
void mhna_prologue(const float* __restrict__ center, ushort* __restrict__ centerBf,
                   const float* __restrict__ Wout, const float* __restrict__ Wgate,
                   ushort* __restrict__ Woutb, ushort* __restrict__ Wgb,
                   const float* __restrict__ Wq, const float* __restrict__ Wk,
                   ushort* __restrict__ Mtb) {
  const int blk = blockIdx.x;
  const int t = threadIdx.x;
  if (blk < 2048) {
    const int n4 = 16384 * 256 / 4;
    int i = blk * 256 + t;
    for (; i < n4; i += 2048 * 256) {
      float4 v = ((const float4*)center)[i];
      ushort4 u;
      u.x = f2bf(v.x); u.y = f2bf(v.y); u.z = f2bf(v.z); u.w = f2bf(v.w);
      ((ushort4*)centerBf)[i] = u;
    }
  } else if (blk < 2304) {
    const int n4 = 256 * 512 / 4;
    int i = (blk - 2048) * 256 + t;      // 0..65535 covers both matrices
    const float* s = (i < n4) ? Wout : Wgate;
    ushort* d = (i < n4) ? Woutb : Wgb;
    int j = (i < n4) ? i : i - n4;
    float4 v = ((const float4*)s)[j];
    ushort4 u;
    u.x = f2bf(v.x); u.y = f2bf(v.y); u.z = f2bf(v.z); u.w = f2bf(v.w);
    ((ushort4*)d)[j] = u;
  } else {
    const int n = blk - 2304;            // 0..511
    const int h = n >> 8, dk = n & 255;
    float acc = 0.f;
#pragma unroll 8
    for (int e = 0; e < 128; ++e) {
      float wkv = Wk[(size_t)(h * 128 + e) * 256 + dk];
      float wqv = Wq[(size_t)(h * 128 + e) * 256 + t];
      acc = fmaf(wqv, wkv, acc);
    }
    Mtb[(size_t)n * 256 + t] = f2bf(acc);
  }
}

// ---------------- qM GEMM: qMb[16384][512] = centerBf @ Mtb^T (bf16 out)
// block = 64 rows x 512 cols, 8 waves; wave w owns cols [64w, 64w+64)
__global__ __launch_bounds__(512)
void gemm_qM(const ushort* __restrict__ A, const ushort* __restrict__ W,
             ushort* __restrict__ Cb) {
  const int t = threadIdx.x;
  const int w = t >> 6, l = t & 63;
  const int row0 = blockIdx.x * 64;
  const int col0 = w * 64;
  const int lr = l & 15, lg = l >> 4;

  f4 acc[4][4];
#pragma unroll
  for (int i = 0; i < 4; ++i)
#pragma unroll
    for (int j = 0; j < 4; ++j) acc[i][j] = (f4)0.f;

#pragma unroll 2
  for (int kk = 0; kk < 256; kk += 32) {
    bf8 af[4];
#pragma unroll
    for (int i = 0; i < 4; ++i)
      af[i] = *(const bf8*)(A + (size_t)(row0 + i * 16 + lr) * 256 + kk + lg * 8);
#pragma unroll
    for (int j = 0; j < 4; ++j) {
      bf8 bw = *(const bf8*)(W + (size_t)(col0 + j * 16 + lr) * 256 + kk + lg * 8);
#pragma unroll
      for (int i = 0; i < 4; ++i)
        acc[i][j] = __builtin_amdgcn_mfma_f32_16x16x32_bf16(af[i], bw, acc[i][j], 0, 0, 0);
    }
  }
#pragma unroll
  for (int i = 0; i < 4; ++i)
#pragma unroll
    for (int j = 0; j < 4; ++j)
#pragma unroll
      for (int r = 0; r < 4; ++r)
        Cb[(size_t)(row0 + i * 16 + lg * 4 + r) * 512 + col0 + j * 16 + lr] =
            f2bf(acc[i][j][r]);
}

// ---------------- kC: fused scores/softmax/ctx with MASK-SKIPPED loads -------
// masked neighbors have attn == exactly 0 (expf(-1e9-mx) underflows) -> their
// rows are never needed; skip the 1KB row load entirely (wave-uniform branch).
__global__ __launch_bounds__(256)
void mhna_kC(const float* __restrict__ nbg, const ushort* __restrict__ qMb,
             const float* __restrict__ wts, const int* __restrict__ msk,
             ushort* __restrict__ ctxb) {
  __shared__ float sc_s[2][64];
  __shared__ float at_s[2][64];
  __shared__ float part[4][512];   // per-wave ctx partials [w][h*256+d]
  const int b = blockIdx.x;
  const int t = threadIdx.x;
  const int w = t >> 6, lam = t & 63;

  // lane's mask bit -> 64-bit wave ballot (k = lane index)
  const int mv_l = msk[(size_t)b * 64 + lam];
  const unsigned long long mb = __ballot(mv_l != 0);

  // qM (bf16) -> f32: lane owns d-slice [4lam, 4lam+4) per head
  const ushort4* qm4 = (const ushort4*)(qMb + (size_t)b * 512);
  ushort4 ua = qm4[lam];
  ushort4 ub = qm4[64 + lam];
  f4 qa = {bf2f(ua.x), bf2f(ua.y), bf2f(ua.z), bf2f(ua.w)};
  f4 qb = {bf2f(ub.x), bf2f(ub.y), bf2f(ub.z), bf2f(ub.w)};

  const float4* nb4 = (const float4*)(nbg + (size_t)b * (64 * 256));
  float4 st[16];                     // wave w holds rows k = r*4+w
#pragma unroll
  for (int r = 0; r < 16; ++r) {
    st[r] = make_float4(0.f, 0.f, 0.f, 0.f);
    const int k = r * 4 + w;
    if ((mb >> k) & 1ull) st[r] = nb4[k * 64 + lam];
  }

  // scores: per-lane partial dot + 64-lane DPP reduce (unmasked rows only)
#pragma unroll
  for (int r = 0; r < 16; ++r) {
    const int k = r * 4 + w;
    if ((mb >> k) & 1ull) {
      float4 v = st[r];
      float p0 = v.x * qa.x + v.y * qa.y + v.z * qa.z + v.w * qa.w;
      float p1 = v.x * qb.x + v.y * qb.y + v.z * qb.z + v.w * qb.w;
      float s0 = waveSum63(p0);
      float s1 = waveSum63(p1);
      if (lam == 63) { sc_s[0][k] = s0; sc_s[1][k] = s1; }
    }
  }
  __syncthreads();

  // softmax: wave 0 -> h=0, wave 1 -> h=1 (k = lam; mv_l is this thread's mask)
  if (t < 128) {
    const int h = w;
    float s = sc_s[h][lam];          // garbage if masked -> selected away
    float wv = wts[(size_t)b * 64 + lam];
    s = mv_l ? fmaf(s, 0.08838834764831845f, wv) : -1e9f;
    float mx = bcast63(waveMax63(s));
    float e = __expf(s - mx);
    float sm = bcast63(waveSum63(e));
    at_s[h][lam] = e / sm;
  }
  __syncthreads();

  // ctx partials from registers: lane owns d-slice [4lam,4lam+4), k = r*4+w
  float c0[4] = {0.f, 0.f, 0.f, 0.f};
  float c1[4] = {0.f, 0.f, 0.f, 0.f};
#pragma unroll
  for (int r = 0; r < 16; ++r) {
    const int k = r * 4 + w;
    if ((mb >> k) & 1ull) {
      const float A0 = at_s[0][k];   // uniform addr -> LDS broadcast
      const float A1 = at_s[1][k];
      float4 v = st[r];
      c0[0] = fmaf(A0, v.x, c0[0]); c0[1] = fmaf(A0, v.y, c0[1]);
      c0[2] = fmaf(A0, v.z, c0[2]); c0[3] = fmaf(A0, v.w, c0[3]);
      c1[0] = fmaf(A1, v.x, c1[0]); c1[1] = fmaf(A1, v.y, c1[1]);
      c1[2] = fmaf(A1, v.z, c1[2]); c1[3] = fmaf(A1, v.w, c1[3]);
    }
  }
  f4 p0v = {c0[0], c0[1], c0[2], c0[3]};
  f4 p1v = {c1[0], c1[1], c1[2], c1[3]};
  *(f4*)&part[w][lam * 4]       = p0v;
  *(f4*)&part[w][256 + lam * 4] = p1v;
  __syncthreads();

  // cross-wave reduce + bf16 store: thread t owns feature d = t for both heads
  float r0 = part[0][t] + part[1][t] + part[2][t] + part[3][t];
  float r1 = part[0][256 + t] + part[1][256 + t] + part[2][256 + t] + part[3][256 + t];
  ctxb[(size_t)b * 512 + t] = f2bf(r0);
  ctxb[(size_t)b * 512 + 256 + t] = f2bf(r1);
}

// ---------------- PG: fused P-GEMM + gate-GEMM + sigmoid blend ----------------
// block = 64 rows x 256 cols, 8 waves; wave w owns cols [32w, 32w+32)
// P tile kept in LDS f32 (never touches HBM).
#define LDP 260   // 260 % 32 == 4 -> 2-way (free) bank pattern; 16B-aligned rows
__global__ __launch_bounds__(512)
void mhna_PG(const ushort* __restrict__ ctxb, const ushort* __restrict__ Woutb,
             const ushort* __restrict__ centerBf, const ushort* __restrict__ Wgb,
             const float* __restrict__ centerF, float* __restrict__ out) {
  __shared__ float p_s[64][LDP];
  const int t = threadIdx.x;
  const int w = t >> 6, l = t & 63;
  const int row0 = blockIdx.x * 64;
  const int col0 = w * 32;
  const int lr = l & 15, lg = l >> 4;

  // ---- phase 1: P = multi_ctx @ Wout^T (K=512) ----
  f4 acc1[4][2];
#pragma unroll
  for (int i = 0; i < 4; ++i)
#pragma unroll
    for (int j = 0; j < 2; ++j) acc1[i][j] = (f4)0.f;

#pragma unroll 2
  for (int kk = 0; kk < 512; kk += 32) {
    bf8 af[4];
#pragma unroll
    for (int i = 0; i < 4; ++i)
      af[i] = *(const bf8*)(ctxb + (size_t)(row0 + i * 16 + lr) * 512 + kk + lg * 8);
#pragma unroll
    for (int j = 0; j < 2; ++j) {
      bf8 bw = *(const bf8*)(Woutb + (size_t)(col0 + j * 16 + lr) * 512 + kk + lg * 8);
#pragma unroll
      for (int i = 0; i < 4; ++i)
        acc1[i][j] = __builtin_amdgcn_mfma_f32_16x16x32_bf16(af[i], bw, acc1[i][j], 0, 0, 0);
    }
  }
#pragma unroll
  for (int i = 0; i < 4; ++i)
#pragma unroll
    for (int j = 0; j < 2; ++j)
#pragma unroll
      for (int r = 0; r < 4; ++r)
        p_s[i * 16 + lg * 4 + r][col0 + j * 16 + lr] = acc1[i][j][r];
  __syncthreads();

  // ---- phase 2: gate = center @ Wg1^T + P @ Wg2^T ----
  f4 acc2[4][2];
#pragma unroll
  for (int i = 0; i < 4; ++i)
#pragma unroll
    for (int j = 0; j < 2; ++j) acc2[i][j] = (f4)0.f;

  // pass A: center (bf16 from global), Wg cols [0,256)
#pragma unroll 2
  for (int kk = 0; kk < 256; kk += 32) {
    bf8 af[4];
#pragma unroll
    for (int i = 0; i < 4; ++i)
      af[i] = *(const bf8*)(centerBf + (size_t)(row0 + i * 16 + lr) * 256 + kk + lg * 8);
#pragma unroll
    for (int j = 0; j < 2; ++j) {
      bf8 bw = *(const bf8*)(Wgb + (size_t)(col0 + j * 16 + lr) * 512 + kk + lg * 8);
#pragma unroll
      for (int i = 0; i < 4; ++i)
        acc2[i][j] = __builtin_amdgcn_mfma_f32_16x16x32_bf16(af[i], bw, acc2[i][j], 0, 0, 0);
    }
  }
  // pass B: P (f32 from LDS -> bf16 fragments), Wg cols [256,512)
#pragma unroll 2
  for (int kk = 0; kk < 256; kk += 32) {
    bf8 af[4];
#pragma unroll
    for (int i = 0; i < 4; ++i) {
      f4 x0 = *(const f4*)&p_s[i * 16 + lr][kk + lg * 8];
      f4 x1 = *(const f4*)&p_s[i * 16 + lr][kk + lg * 8 + 4];
      bf8 a;
      a[0] = (short)f2bf(x0.x); a[1] = (short)f2bf(x0.y);
      a[2] = (short)f2bf(x0.z); a[3] = (short)f2bf(x0.w);
      a[4] = (short)f2bf(x1.x); a[5] = (short)f2bf(x1.y);
      a[6] = (short)f2bf(x1.z); a[7] = (short)f2bf(x1.w);
      af[i] = a;
    }
#pragma unroll
    for (int j = 0; j < 2; ++j) {
      bf8 bw = *(const bf8*)(Wgb + (size_t)(col0 + j * 16 + lr) * 512 + 256 + kk + lg * 8);
#pragma unroll
      for (int i = 0; i < 4; ++i)
        acc2[i][j] = __builtin_amdgcn_mfma_f32_16x16x32_bf16(af[i], bw, acc2[i][j], 0, 0, 0);
    }
  }

  // ---- epilogue: gate blend (P f32 from LDS) ----
#pragma unroll
  for (int i = 0; i < 4; ++i)
#pragma unroll
    for (int j = 0; j < 2; ++j)
#pragma unroll
      for (int r = 0; r < 4; ++r) {
        const int lrow = i * 16 + lg * 4 + r;
        const int row = row0 + lrow;
        const int col = col0 + j * 16 + lr;
        float g = 1.f / (1.f + __expf(-acc2[i][j][r]));
        float pv = p_s[lrow][col];
        float cv = centerF[(size_t)row * 256 + col];
        out[(size_t)row * 256 + col] = g * cv + (1.f - g) * pv;
      }
}

extern "C" void kernel_launch(void* const* d_in, const int* in_sizes, int n_in,
                              void* d_out, int out_size, void* d_ws, size_t ws_size,
                              hipStream_t stream) {
  const float* center = (const float*)d_in[0];
  const float* neigh  = (const float*)d_in[1];
  const float* nw     = (const float*)d_in[2];
  const int*   nm     = (const int*)d_in[3];
  const float* Wq     = (const float*)d_in[4];
  const float* Wk     = (const float*)d_in[5];
  const float* Wout   = (const float*)d_in[6];
  const float* Wgate  = (const float*)d_in[7];
  float* out = (float*)d_out;

  char* ws = (char*)d_ws;
  size_t off = 0;
  ushort* Mtb      = (ushort*)(ws + off); off += (size_t)512 * 256 * 2;        // 256 KB
  ushort* centerBf = (ushort*)(ws + off); off += (size_t)16384 * 256 * 2;      // 8 MB
  ushort* qMb      = (ushort*)(ws + off); off += (size_t)16384 * 512 * 2;      // 16 MB
  ushort* ctxb     = (ushort*)(ws + off); off += (size_t)16384 * 512 * 2;      // 16 MB
  ushort* Woutb    = (ushort*)(ws + off); off += (size_t)256 * 512 * 2;        // 256 KB
  ushort* Wgb      = (ushort*)(ws + off); off += (size_t)256 * 512 * 2;        // 256 KB

  // prologue: center cast + weight casts + Mt = Wq^T Wk (one launch)
  mhna_prologue<<<2816, 256, 0, stream>>>(center, centerBf, Wout, Wgate,
                                          Woutb, Wgb, Wq, Wk, Mtb);
  // qM = center @ Mt^T : [16384 x 512] bf16, K=256
  gemm_qM<<<256, 512, 0, stream>>>(centerBf, Mtb, qMb);
  // fused neighborhood attention (mask-skipped neighbor loads)
  mhna_kC<<<16384, 256, 0, stream>>>(neigh, qMb, nw, nm, ctxb);
  // fused: P = ctx @ Wout^T ; gate = sigmoid([center,P] @ Wg^T) ; blend
  mhna_PG<<<256, 512, 0, stream>>>(ctxb, Woutb, centerBf, Wgb, center, out);
}